// Round 13
// baseline (389.308 us; speedup 1.0000x reference)
//
#include <hip/hip_runtime.h>

#define BB 16
#define SS 1024
#define HH 768
#define JJ 5
#define WHJ (HH*HH)
#define RIDX_J (BB*SS)                  /* 16384 rows max per head */
#define NSEG 8

typedef __attribute__((ext_vector_type(4))) _Float16 h4_t;
typedef __attribute__((ext_vector_type(8))) _Float16 h8_t;
typedef __attribute__((ext_vector_type(4))) float f32x4;

#define WH_HALVES (JJ*HH*HH)            /* 2949120  */
#define WH_BYTES  (WH_HALVES*2)         /* 5898240  */
#define HID_HALVES (BB*SS*HH)           /* 12582912 */
#define HID_BYTES (HID_HALVES*2)        /* 25165824 */
#define SC_FLOATS (BB*JJ*SS)            /* 81920    */
#define SC_BYTES  (SC_FLOATS*4)         /* 327680   */
#define RIDX_BYTES (JJ*RIDX_J*4)        /* 327680   */
#define FINAL_W   (JJ*2*HH + HH)        /* 8448     */
#define OUT2_OFF  (BB*FINAL_W)          /* 135168   */

#define NB_CONV (HID_HALVES/4/256)      /* 12288 */
#define NB_IDX  (JJ*BB)                 /* 80    */
#define NB_TAIL (BB)                    /* 16    */

// ---------------------------------------------------------------------------
// Kernel 0 (fused): convert W+hidden f32->fp16, zero scores, MFMA layout
// self-test -> meta[5]; extra blocks: span row-index build (meta[j], ridx)
// and out zero + full_emb tail copy.
// ---------------------------------------------------------------------------
__global__ void k_convert(const float* __restrict__ W, const float* __restrict__ hidden,
                          const float* __restrict__ full_emb, const int* __restrict__ spans,
                          _Float16* __restrict__ Wh, _Float16* __restrict__ Hh,
                          float* __restrict__ scores, int* __restrict__ ridx,
                          int* __restrict__ meta, float* __restrict__ out)
{
    const int bid = blockIdx.x, tid = threadIdx.x;
    __shared__ int cnts[BB];

    if (bid < NB_CONV) {
        int i = bid * 256 + tid;
        {
            float4 v = *(const float4*)(hidden + (size_t)i * 4);
            h4_t hv = { (_Float16)v.x, (_Float16)v.y, (_Float16)v.z, (_Float16)v.w };
            *(h4_t*)(Hh + (size_t)i * 4) = hv;
        }
        if (i < WH_HALVES / 4) {
            float4 v = *(const float4*)(W + (size_t)i * 4);
            h4_t hv = { (_Float16)v.x, (_Float16)v.y, (_Float16)v.z, (_Float16)v.w };
            *(h4_t*)(Wh + (size_t)i * 4) = hv;
        }
        if (i < SC_FLOATS) scores[i] = 0.f;

        if (bid == 0 && tid < 64) {
            // --- MFMA A/B fragment k-mapping self-test ---
            int l = tid, l15 = l & 15, lg = l >> 4;
            h8_t a1, b1, a2, b2;
#pragma unroll
            for (int jj = 0; jj < 8; ++jj) {
                int k1 = (jj & 3) + 4 * lg + 16 * (jj >> 2);
                int k2 = jj + 8 * lg;
                a1[jj] = (_Float16)(float)((l15 * 31 + k1 * 17) % 13 - 6);
                b1[jj] = (_Float16)(float)((k1 * 7 + l15 * 5) % 11 - 5);
                a2[jj] = (_Float16)(float)((l15 * 31 + k2 * 17) % 13 - 6);
                b2[jj] = (_Float16)(float)((k2 * 7 + l15 * 5) % 11 - 5);
            }
            f32x4 z = { 0.f, 0.f, 0.f, 0.f };
            f32x4 c1 = __builtin_amdgcn_mfma_f32_16x16x32_f16(a1, b1, z, 0, 0, 0);
            f32x4 c2 = __builtin_amdgcn_mfma_f32_16x16x32_f16(a2, b2, z, 0, 0, 0);
            int ok1 = 1, ok2 = 1;
#pragma unroll
            for (int r = 0; r < 4; ++r) {
                int row = lg * 4 + r;
                float ref = 0.f;
                for (int k = 0; k < 32; ++k)
                    ref += (float)((row * 31 + k * 17) % 13 - 6) *
                           (float)((k * 7 + l15 * 5) % 11 - 5);
                ok1 &= (c1[r] == ref);
                ok2 &= (c2[r] == ref);
            }
            int all1 = __all(ok1);
            int all2 = __all(ok2);
            if (l == 0) meta[5] = all1 ? 1 : (all2 ? 2 : 0);
        }
        return;
    }

    if (bid < NB_CONV + NB_IDX) {
        // --- gathered row index build, one block per (j,b) ---
        const int seg = bid - NB_CONV;
        const int j = seg / BB, b = seg % BB;
        if (tid < BB) {
            int st = spans[(tid * JJ + j) * 2 + 0];
            int en = spans[(tid * JJ + j) * 2 + 1];
            cnts[tid] = (en > st) ? (en - st) : 0;
        }
        __syncthreads();
        if (b == 0 && tid == 0) {
            int tot = 0;
            for (int b2 = 0; b2 < BB; ++b2) tot += cnts[b2];
            meta[j] = tot;
        }
        int off = 0;
        for (int b2 = 0; b2 < b; ++b2) off += cnts[b2];
        const int st = spans[(b * JJ + j) * 2 + 0];
        const int cnt = cnts[b];
        const int base = j * RIDX_J + off;
        for (int i = tid; i < cnt; i += 256)
            ridx[base + i] = b * SS + st + i;
        return;
    }

    // --- tail: zero span region of out[b], copy full_emb into both outputs ---
    {
        const int b = bid - NB_CONV - NB_IDX;
        float* ob = out + (size_t)b * FINAL_W;
        for (int h = tid; h < JJ * 2 * HH; h += 256) ob[h] = 0.f;
        for (int h = tid; h < HH; h += 256) {
            float v = full_emb[b * HH + h];
            ob[JJ * 2 * HH + h] = v;
            out[OUT2_OFF + b * HH + h] = v;
        }
    }
}

// ---------------------------------------------------------------------------
// Kernel 1: gathered dense GEMM per head. R7-proven per-wave body scaled to
// BM=256 (512 threads, 8 waves, wave tile 64x64 unchanged, acc[4][4]
// unchanged): -23% staged LDS bytes, -50% L2 B-refetch, 24 waves/CU
// (3 blocks x 8 waves). Same single-buffer reg-staged loop, same barriers,
// same fragment layouts — no pipelining (5 variants all regressed).
// ---------------------------------------------------------------------------
__device__ __forceinline__ void epilogue(
    f32x4 (&acc)[4][4], const float* qv, const float* bvec, float* scores,
    const int* s_ridx, float* s_red, int j, int nblk, int valid_rows,
    int tid, int wm, int wn, int lg, int l15)
{
    float qn[4], bn[4];
#pragma unroll
    for (int c = 0; c < 4; ++c) {
        int col = nblk * 128 + wn * 64 + c * 16 + l15;
        qn[c] = qv[col];
        bn[c] = bvec[col];
    }
#pragma unroll
    for (int a = 0; a < 4; ++a) {
#pragma unroll
        for (int rr = 0; rr < 4; ++rr) {
            float ssum = 0.f;
#pragma unroll
            for (int c = 0; c < 4; ++c) {
                float yv = acc[a][c][rr] + bn[c];
                yv = fminf(fmaxf(yv, -15.f), 15.f);
                float e = __expf(2.f * yv);
                ssum += qn[c] * ((e - 1.f) / (e + 1.f));
            }
#pragma unroll
            for (int off = 1; off < 16; off <<= 1)
                ssum += __shfl_xor(ssum, off, 64);
            if (l15 == 0)
                s_red[(wm * 2 + wn) * 64 + a * 16 + lg * 4 + rr] = ssum;
        }
    }
    __syncthreads();
    if (tid < valid_rows) {
        int wm2 = tid >> 6, rl = tid & 63;
        float v = s_red[(wm2 * 2) * 64 + rl] + s_red[(wm2 * 2 + 1) * 64 + rl];
        int gidx = s_ridx[tid];
        atomicAdd(&scores[(gidx >> 10) * (JJ * SS) + j * SS + (gidx & 1023)], v);
    }
}

template<int LAYOUT>
__device__ __forceinline__ void scores_reg(
    const _Float16* __restrict__ Hh, const _Float16* __restrict__ wj,
    const float* __restrict__ qv, const float* __restrict__ bvec,
    float* __restrict__ scores, const int* s_ridx,
    _Float16* Alds, _Float16* Blds, float* s_red,
    int j, int nblk, int valid_rows, int tid)
{
    // A staging: thread -> (row r of 256, k-half hh), 4 x h8 per K-step.
    const int r  = tid >> 1, hh = tid & 1;
    const int mf = r >> 4,  mr = r & 15;            // mf in 0..15
    const _Float16* ap = Hh + (size_t)s_ridx[r] * HH + hh * 32;

    // B staging: thread -> (row rb of 128, k-quarter q), 2 x h8 per K-step.
    const int rb = tid >> 2, q = tid & 3;
    const int mfB = rb >> 4, mrB = rb & 15;         // mfB in 0..7
    const _Float16* bp = wj + (size_t)(nblk * 128 + rb) * HH + q * 16;

    const int wave = tid >> 6, lane = tid & 63;     // wave in 0..7
    const int l15 = lane & 15, lg = lane >> 4;
    const int wm = wave >> 1, wn = wave & 1;        // wm 0..3, wn 0..1

    f32x4 acc[4][4];
#pragma unroll
    for (int a = 0; a < 4; ++a)
#pragma unroll
        for (int c = 0; c < 4; ++c) acc[a][c] = (f32x4){0.f, 0.f, 0.f, 0.f};

    for (int ks = 0; ks < 12; ++ks) {
        h8_t av[4], bv2[2];
        const _Float16* a0 = ap + ks * 64;
        const _Float16* b0 = bp + ks * 64;
#pragma unroll
        for (int g2 = 0; g2 < 4; ++g2)
            av[g2] = *(const h8_t*)(a0 + g2 * 8);
#pragma unroll
        for (int u = 0; u < 2; ++u)
            bv2[u] = *(const h8_t*)(b0 + u * 8);
        __syncthreads();
        if (LAYOUT == 2) {
#pragma unroll
            for (int g2 = 0; g2 < 4; ++g2) {
                int c = ((mf * 2 + hh) * 4 + g2) * 16 + mr;
                *(h8_t*)(Alds + c * 8) = av[g2];
            }
#pragma unroll
            for (int u = 0; u < 2; ++u) {
                int ka = q * 16 + u * 8;            // 0..56, offset in 64-k step
                int c = ((mfB * 2 + (ka >> 5)) * 4 + ((ka & 31) >> 3)) * 16 + mrB;
                *(h8_t*)(Blds + c * 8) = bv2[u];
            }
        } else {
#pragma unroll
            for (int g2 = 0; g2 < 4; ++g2) {
                int k0a = g2 * 8, k0b = g2 * 8 + 4;
                int ga = (k0a & 15) >> 2, ja = (k0a >> 4) << 2;
                int gb = (k0b & 15) >> 2, jb = (k0b >> 4) << 2;
                int cA = ((mf * 2 + hh) * 4 + ga) * 16 + mr;
                int cB = ((mf * 2 + hh) * 4 + gb) * 16 + mr;
                h8_t x = av[g2];
                h4_t alo = { x[0], x[1], x[2], x[3] };
                h4_t ahi = { x[4], x[5], x[6], x[7] };
                *(h4_t*)(Alds + cA * 8 + ja) = alo;
                *(h4_t*)(Alds + cB * 8 + jb) = ahi;
            }
#pragma unroll
            for (int u = 0; u < 2; ++u) {
                h8_t y = bv2[u];
#pragma unroll
                for (int v = 0; v < 2; ++v) {       // two h4 halves at +0, +4
                    int k = q * 16 + u * 8 + v * 4; // absolute offset in 64-k step
                    int kk = k & 31;
                    int g = (kk & 15) >> 2, j0 = (kk >> 4) << 2;
                    int c = ((mfB * 2 + (k >> 5)) * 4 + g) * 16 + mrB;
                    h4_t hv = { y[v * 4 + 0], y[v * 4 + 1], y[v * 4 + 2], y[v * 4 + 3] };
                    *(h4_t*)(Blds + c * 8 + j0) = hv;
                }
            }
        }
        __syncthreads();
#pragma unroll
        for (int ks2 = 0; ks2 < 2; ++ks2) {
            h8_t af[4], bf[4];
#pragma unroll
            for (int f = 0; f < 4; ++f) {
                int ca = (((wm * 4 + f) * 2 + ks2) * 4 + lg) * 16 + l15;
                af[f] = *(const h8_t*)(Alds + ca * 8);
                int cb = (((wn * 4 + f) * 2 + ks2) * 4 + lg) * 16 + l15;
                bf[f] = *(const h8_t*)(Blds + cb * 8);
            }
#pragma unroll
            for (int a = 0; a < 4; ++a)
#pragma unroll
                for (int c = 0; c < 4; ++c)
                    acc[a][c] = __builtin_amdgcn_mfma_f32_16x16x32_f16(
                        af[a], bf[c], acc[a][c], 0, 0, 0);
        }
    }
    epilogue(acc, qv, bvec, scores, s_ridx, s_red, j, nblk, valid_rows,
             tid, wm, wn, lg, l15);
}

__global__ __launch_bounds__(512, 6) void k_scores(
    const _Float16* __restrict__ Hh, const _Float16* __restrict__ Wh,
    const float* __restrict__ attn_b, const float* __restrict__ attn_q,
    float* __restrict__ scores, const int* __restrict__ ridx,
    const int* __restrict__ meta)
{
    const int tile = blockIdx.x, nblk = blockIdx.y, j = blockIdx.z;
    const int Mj = meta[j];
    const int rows_base = tile * 256;
    if (rows_base >= Mj) return;
    const int valid_rows = min(256, Mj - rows_base);

    __shared__ __align__(16) _Float16 Alds[2048 * 8];   // 32768 B
    __shared__ __align__(16) _Float16 Blds[1024 * 8];   // 16384 B
    __shared__ int   s_ridx[256];
    __shared__ float s_red[512];

    const int tid = threadIdx.x;
    if (tid < 256)
        s_ridx[tid] = ridx[j * RIDX_J + rows_base + min(tid, valid_rows - 1)];
    __syncthreads();

    const _Float16* wj = Wh + (size_t)j * WHJ;
    const float* qv = attn_q + j * HH;
    const float* bv = attn_b + j * HH;

    if (meta[5] == 2)
        scores_reg<2>(Hh, wj, qv, bv, scores, s_ridx, Alds, Blds, s_red,
                      j, nblk, valid_rows, tid);
    else
        scores_reg<1>(Hh, wj, qv, bv, scores, s_ridx, Alds, Blds, s_red,
                      j, nblk, valid_rows, tid);
}

// ---------------------------------------------------------------------------
// Kernel 2: fused softmax + segmented pooling. Grid (bj, seg): each block
// computes full-span softmax stats, then pools rows [i0,i1) with a x4
// row-unrolled pipeline; partials atomicAdd'ed into pre-zeroed out.
// ---------------------------------------------------------------------------
__global__ __launch_bounds__(256) void k_pool(
    const _Float16* __restrict__ Hh, const float* __restrict__ scores,
    const int* __restrict__ spans, float* __restrict__ out)
{
    const int bj = blockIdx.x, seg = blockIdx.y;
    const int b = bj / JJ, j = bj % JJ;
    const int start = spans[bj * 2 + 0];
    const int end   = spans[bj * 2 + 1];
    const int count = end - start;
    if (count <= 0) return;                    // out already zeroed

    const int tid = threadIdx.x;
    const float* sc = scores + bj * SS;
    __shared__ float red[8];
    __shared__ float wl[SS / NSEG + 1];

    // --- softmax stats over the FULL span ---
    float lm = -3.0e38f;
    for (int s = start + tid; s < end; s += 256) lm = fmaxf(lm, sc[s]);
#pragma unroll
    for (int off = 32; off > 0; off >>= 1) lm = fmaxf(lm, __shfl_xor(lm, off, 64));
    int wid = tid >> 6, lane = tid & 63;
    if (lane == 0) red[wid] = lm;
    __syncthreads();
    float m = fmaxf(fmaxf(red[0], red[1]), fmaxf(red[2], red[3]));

    float ld = 0.f;
    for (int s = start + tid; s < end; s += 256) ld += __expf(sc[s] - m);
#pragma unroll
    for (int off = 32; off > 0; off >>= 1) ld += __shfl_xor(ld, off, 64);
    if (lane == 0) red[4 + wid] = ld;
    __syncthreads();
    float inv_d = 1.f / (red[4] + red[5] + red[6] + red[7]);

    // --- this block's row segment ---
    const int i0 = start + (count * seg) / NSEG;
    const int i1 = start + (count * (seg + 1)) / NSEG;
    for (int s = i0 + tid; s < i1; s += 256)
        wl[s - i0] = __expf(sc[s] - m) * inv_d;
    __syncthreads();

    if (tid < 192) {
        float am[4] = {0.f, 0.f, 0.f, 0.f}, aa[4] = {0.f, 0.f, 0.f, 0.f};
        const _Float16* hp = Hh + (size_t)b * SS * HH + tid * 4;
        const int n = i1 - i0;
        int i = 0;
        for (; i + 4 <= n; i += 4) {
            h4_t v0 = *(const h4_t*)(hp + (size_t)(i0 + i + 0) * HH);
            h4_t v1 = *(const h4_t*)(hp + (size_t)(i0 + i + 1) * HH);
            h4_t v2 = *(const h4_t*)(hp + (size_t)(i0 + i + 2) * HH);
            h4_t v3 = *(const h4_t*)(hp + (size_t)(i0 + i + 3) * HH);
            float w0 = wl[i], w1 = wl[i + 1], w2 = wl[i + 2], w3 = wl[i + 3];
#pragma unroll
            for (int c = 0; c < 4; ++c) {
                float x0 = (float)v0[c], x1 = (float)v1[c];
                float x2 = (float)v2[c], x3 = (float)v3[c];
                am[c] += (x0 + x1) + (x2 + x3);
                aa[c] += (w0 * x0 + w1 * x1) + (w2 * x2 + w3 * x3);
            }
        }
        for (; i < n; ++i) {
            h4_t v = *(const h4_t*)(hp + (size_t)(i0 + i) * HH);
            float w = wl[i];
#pragma unroll
            for (int c = 0; c < 4; ++c) {
                float x = (float)v[c];
                am[c] += x;
                aa[c] += w * x;
            }
        }
        float inv = 1.f / (float)count;
        float* fin = out + (size_t)b * FINAL_W + j * (2 * HH);
#pragma unroll
        for (int c = 0; c < 4; ++c) {
            atomicAdd(&fin[tid * 4 + c], am[c] * inv);
            atomicAdd(&fin[HH + tid * 4 + c], aa[c]);
        }
    }
}

// ---------------------------------------------------------------------------
extern "C" void kernel_launch(void* const* d_in, const int* in_sizes, int n_in,
                              void* d_out, int out_size, void* d_ws, size_t ws_size,
                              hipStream_t stream)
{
    const float* hidden   = (const float*)d_in[0];
    const float* full_emb = (const float*)d_in[1];
    const float* attn_W   = (const float*)d_in[2];
    const float* attn_b   = (const float*)d_in[3];
    const float* attn_q   = (const float*)d_in[4];
    const int*   spans    = (const int*)d_in[5];
    float* out = (float*)d_out;

    char* ws = (char*)d_ws;
    _Float16* Wh  = (_Float16*)ws;
    _Float16* Hh  = (_Float16*)(ws + WH_BYTES);
    float* scores = (float*)(ws + WH_BYTES + HID_BYTES);
    int*   ridx   = (int*)(ws + WH_BYTES + HID_BYTES + SC_BYTES);
    int*   meta   = (int*)(ws + WH_BYTES + HID_BYTES + SC_BYTES + RIDX_BYTES);

    k_convert<<<NB_CONV + NB_IDX + NB_TAIL, 256, 0, stream>>>(
        attn_W, hidden, full_emb, spans, Wh, Hh, scores, ridx, meta, out);
    k_scores<<<dim3(RIDX_J / 256, HH / 128, JJ), 512, 0, stream>>>(
        Hh, Wh, attn_b, attn_q, scores, ridx, meta);
    k_pool<<<dim3(BB * JJ, NSEG), 256, 0, stream>>>(Hh, scores, spans, out);
}

// Round 14
// 117.218 us; speedup vs baseline: 3.3212x; 3.3212x over previous
//
#include <hip/hip_runtime.h>

#define BB 16
#define SS 1024
#define HH 768
#define JJ 5
#define WHJ (HH*HH)
#define RIDX_J (BB*SS)                  /* 16384 rows max per head */
#define NSEG 8

typedef __attribute__((ext_vector_type(4))) _Float16 h4_t;
typedef __attribute__((ext_vector_type(8))) _Float16 h8_t;
typedef __attribute__((ext_vector_type(4))) float f32x4;

#define WH_HALVES (JJ*HH*HH)            /* 2949120  */
#define WH_BYTES  (WH_HALVES*2)         /* 5898240  */
#define HID_HALVES (BB*SS*HH)           /* 12582912 */
#define HID_BYTES (HID_HALVES*2)        /* 25165824 */
#define SC_FLOATS (BB*JJ*SS)            /* 81920    */
#define SC_BYTES  (SC_FLOATS*4)         /* 327680   */
#define RIDX_BYTES (JJ*RIDX_J*4)        /* 327680   */
#define FINAL_W   (JJ*2*HH + HH)        /* 8448     */
#define OUT2_OFF  (BB*FINAL_W)          /* 135168   */

#define NB_CONV (HID_HALVES/4/256)      /* 12288 */
#define NB_IDX  (JJ*BB)                 /* 80    */
#define NB_TAIL (BB)                    /* 16    */

// ---------------------------------------------------------------------------
// Kernel 0 (fused): convert W+hidden f32->fp16, zero scores, MFMA layout
// self-test -> meta[5]; extra blocks: span row-index build (meta[j], ridx)
// and out zero + full_emb tail copy.
// ---------------------------------------------------------------------------
__global__ void k_convert(const float* __restrict__ W, const float* __restrict__ hidden,
                          const float* __restrict__ full_emb, const int* __restrict__ spans,
                          _Float16* __restrict__ Wh, _Float16* __restrict__ Hh,
                          float* __restrict__ scores, int* __restrict__ ridx,
                          int* __restrict__ meta, float* __restrict__ out)
{
    const int bid = blockIdx.x, tid = threadIdx.x;
    __shared__ int cnts[BB];

    if (bid < NB_CONV) {
        int i = bid * 256 + tid;
        {
            float4 v = *(const float4*)(hidden + (size_t)i * 4);
            h4_t hv = { (_Float16)v.x, (_Float16)v.y, (_Float16)v.z, (_Float16)v.w };
            *(h4_t*)(Hh + (size_t)i * 4) = hv;
        }
        if (i < WH_HALVES / 4) {
            float4 v = *(const float4*)(W + (size_t)i * 4);
            h4_t hv = { (_Float16)v.x, (_Float16)v.y, (_Float16)v.z, (_Float16)v.w };
            *(h4_t*)(Wh + (size_t)i * 4) = hv;
        }
        if (i < SC_FLOATS) scores[i] = 0.f;

        if (bid == 0 && tid < 64) {
            // --- MFMA A/B fragment k-mapping self-test ---
            int l = tid, l15 = l & 15, lg = l >> 4;
            h8_t a1, b1, a2, b2;
#pragma unroll
            for (int jj = 0; jj < 8; ++jj) {
                int k1 = (jj & 3) + 4 * lg + 16 * (jj >> 2);
                int k2 = jj + 8 * lg;
                a1[jj] = (_Float16)(float)((l15 * 31 + k1 * 17) % 13 - 6);
                b1[jj] = (_Float16)(float)((k1 * 7 + l15 * 5) % 11 - 5);
                a2[jj] = (_Float16)(float)((l15 * 31 + k2 * 17) % 13 - 6);
                b2[jj] = (_Float16)(float)((k2 * 7 + l15 * 5) % 11 - 5);
            }
            f32x4 z = { 0.f, 0.f, 0.f, 0.f };
            f32x4 c1 = __builtin_amdgcn_mfma_f32_16x16x32_f16(a1, b1, z, 0, 0, 0);
            f32x4 c2 = __builtin_amdgcn_mfma_f32_16x16x32_f16(a2, b2, z, 0, 0, 0);
            int ok1 = 1, ok2 = 1;
#pragma unroll
            for (int r = 0; r < 4; ++r) {
                int row = lg * 4 + r;
                float ref = 0.f;
                for (int k = 0; k < 32; ++k)
                    ref += (float)((row * 31 + k * 17) % 13 - 6) *
                           (float)((k * 7 + l15 * 5) % 11 - 5);
                ok1 &= (c1[r] == ref);
                ok2 &= (c2[r] == ref);
            }
            int all1 = __all(ok1);
            int all2 = __all(ok2);
            if (l == 0) meta[5] = all1 ? 1 : (all2 ? 2 : 0);
        }
        return;
    }

    if (bid < NB_CONV + NB_IDX) {
        // --- gathered row index build, one block per (j,b) ---
        const int seg = bid - NB_CONV;
        const int j = seg / BB, b = seg % BB;
        if (tid < BB) {
            int st = spans[(tid * JJ + j) * 2 + 0];
            int en = spans[(tid * JJ + j) * 2 + 1];
            cnts[tid] = (en > st) ? (en - st) : 0;
        }
        __syncthreads();
        if (b == 0 && tid == 0) {
            int tot = 0;
            for (int b2 = 0; b2 < BB; ++b2) tot += cnts[b2];
            meta[j] = tot;
        }
        int off = 0;
        for (int b2 = 0; b2 < b; ++b2) off += cnts[b2];
        const int st = spans[(b * JJ + j) * 2 + 0];
        const int cnt = cnts[b];
        const int base = j * RIDX_J + off;
        for (int i = tid; i < cnt; i += 256)
            ridx[base + i] = b * SS + st + i;
        return;
    }

    // --- tail: zero span region of out[b], copy full_emb into both outputs ---
    {
        const int b = bid - NB_CONV - NB_IDX;
        float* ob = out + (size_t)b * FINAL_W;
        for (int h = tid; h < JJ * 2 * HH; h += 256) ob[h] = 0.f;
        for (int h = tid; h < HH; h += 256) {
            float v = full_emb[b * HH + h];
            ob[JJ * 2 * HH + h] = v;
            out[OUT2_OFF + b * HH + h] = v;
        }
    }
}

// ---------------------------------------------------------------------------
// Kernel 1: gathered dense GEMM per head (R7-proven body, byte-for-byte).
// BM=BN=128, BK=64, 4 waves, reg-staged single-buffer LDS, 4 blocks/CU.
// Seven variants (gll, gll-dbuf, B-direct, reg-dbuf, raw-barrier, BM=256,
// XCD-chunk) all regressed 1.4-4.9x — cross-block TLP at 4 blocks/CU with
// a 124-reg footprint is the working point; do not restructure.
// ---------------------------------------------------------------------------
__device__ __forceinline__ void epilogue(
    f32x4 (&acc)[4][4], const float* qv, const float* bvec, float* scores,
    const int* s_ridx, float* s_red, int j, int nblk, int valid_rows,
    int tid, int wm, int wn, int lg, int l15)
{
    float qn[4], bn[4];
#pragma unroll
    for (int c = 0; c < 4; ++c) {
        int col = nblk * 128 + wn * 64 + c * 16 + l15;
        qn[c] = qv[col];
        bn[c] = bvec[col];
    }
#pragma unroll
    for (int a = 0; a < 4; ++a) {
#pragma unroll
        for (int rr = 0; rr < 4; ++rr) {
            float ssum = 0.f;
#pragma unroll
            for (int c = 0; c < 4; ++c) {
                float yv = acc[a][c][rr] + bn[c];
                yv = fminf(fmaxf(yv, -15.f), 15.f);
                float e = __expf(2.f * yv);
                ssum += qn[c] * ((e - 1.f) / (e + 1.f));
            }
#pragma unroll
            for (int off = 1; off < 16; off <<= 1)
                ssum += __shfl_xor(ssum, off, 64);
            if (l15 == 0)
                s_red[(wm * 2 + wn) * 64 + a * 16 + lg * 4 + rr] = ssum;
        }
    }
    __syncthreads();
    if (tid < valid_rows) {
        int wm2 = tid >> 6, rl = tid & 63;
        float v = s_red[(wm2 * 2) * 64 + rl] + s_red[(wm2 * 2 + 1) * 64 + rl];
        int gidx = s_ridx[tid];
        atomicAdd(&scores[(gidx >> 10) * (JJ * SS) + j * SS + (gidx & 1023)], v);
    }
}

template<int LAYOUT>
__device__ __forceinline__ void scores_reg(
    const _Float16* __restrict__ Hh, const _Float16* __restrict__ wj,
    const float* __restrict__ qv, const float* __restrict__ bvec,
    float* __restrict__ scores, const int* s_ridx,
    _Float16* Alds, _Float16* Blds, float* s_red,
    int j, int nblk, int valid_rows, int tid)
{
    const int r  = tid >> 1, hh = tid & 1;
    const int mf = r >> 4,  mr = r & 15;
    const _Float16* ap = Hh + (size_t)s_ridx[r] * HH + hh * 32;
    const _Float16* bp = wj + (size_t)(nblk * 128 + r) * HH + hh * 32;

    const int wave = tid >> 6, lane = tid & 63;
    const int l15 = lane & 15, lg = lane >> 4;
    const int wm = wave >> 1, wn = wave & 1;

    f32x4 acc[4][4];
#pragma unroll
    for (int a = 0; a < 4; ++a)
#pragma unroll
        for (int c = 0; c < 4; ++c) acc[a][c] = (f32x4){0.f, 0.f, 0.f, 0.f};

    for (int ks = 0; ks < 12; ++ks) {
        h8_t av[4], bv4[4];
        const _Float16* a0 = ap + ks * 64;
        const _Float16* b0 = bp + ks * 64;
#pragma unroll
        for (int g2 = 0; g2 < 4; ++g2) {
            av[g2]  = *(const h8_t*)(a0 + g2 * 8);
            bv4[g2] = *(const h8_t*)(b0 + g2 * 8);
        }
        __syncthreads();
        if (LAYOUT == 2) {
#pragma unroll
            for (int g2 = 0; g2 < 4; ++g2) {
                int c = ((mf * 2 + hh) * 4 + g2) * 16 + mr;
                *(h8_t*)(Alds + c * 8) = av[g2];
                *(h8_t*)(Blds + c * 8) = bv4[g2];
            }
        } else {
#pragma unroll
            for (int g2 = 0; g2 < 4; ++g2) {
                int k0a = g2 * 8, k0b = g2 * 8 + 4;
                int ga = (k0a & 15) >> 2, ja = (k0a >> 4) << 2;
                int gb = (k0b & 15) >> 2, jb = (k0b >> 4) << 2;
                int cA = ((mf * 2 + hh) * 4 + ga) * 16 + mr;
                int cB = ((mf * 2 + hh) * 4 + gb) * 16 + mr;
                h8_t x = av[g2];
                h4_t alo = { x[0], x[1], x[2], x[3] };
                h4_t ahi = { x[4], x[5], x[6], x[7] };
                *(h4_t*)(Alds + cA * 8 + ja) = alo;
                *(h4_t*)(Alds + cB * 8 + jb) = ahi;
                h8_t y = bv4[g2];
                h4_t blo = { y[0], y[1], y[2], y[3] };
                h4_t bhi = { y[4], y[5], y[6], y[7] };
                *(h4_t*)(Blds + cA * 8 + ja) = blo;
                *(h4_t*)(Blds + cB * 8 + jb) = bhi;
            }
        }
        __syncthreads();
#pragma unroll
        for (int ks2 = 0; ks2 < 2; ++ks2) {
            h8_t af[4], bf[4];
#pragma unroll
            for (int f = 0; f < 4; ++f) {
                int ca = (((wm * 4 + f) * 2 + ks2) * 4 + lg) * 16 + l15;
                af[f] = *(const h8_t*)(Alds + ca * 8);
                int cb = (((wn * 4 + f) * 2 + ks2) * 4 + lg) * 16 + l15;
                bf[f] = *(const h8_t*)(Blds + cb * 8);
            }
#pragma unroll
            for (int a = 0; a < 4; ++a)
#pragma unroll
                for (int c = 0; c < 4; ++c)
                    acc[a][c] = __builtin_amdgcn_mfma_f32_16x16x32_f16(
                        af[a], bf[c], acc[a][c], 0, 0, 0);
        }
    }
    epilogue(acc, qv, bvec, scores, s_ridx, s_red, j, nblk, valid_rows,
             tid, wm, wn, lg, l15);
}

__global__ __launch_bounds__(256, 4) void k_scores(
    const _Float16* __restrict__ Hh, const _Float16* __restrict__ Wh,
    const float* __restrict__ attn_b, const float* __restrict__ attn_q,
    float* __restrict__ scores, const int* __restrict__ ridx,
    const int* __restrict__ meta)
{
    const int tile = blockIdx.x, nblk = blockIdx.y, j = blockIdx.z;
    const int Mj = meta[j];
    const int rows_base = tile * 128;
    if (rows_base >= Mj) return;
    const int valid_rows = min(128, Mj - rows_base);

    __shared__ __align__(16) _Float16 Alds[1024 * 8];   // 16384 B
    __shared__ __align__(16) _Float16 Blds[1024 * 8];   // 16384 B
    __shared__ int   s_ridx[128];
    __shared__ float s_red[256];

    const int tid = threadIdx.x;
    if (tid < 128)
        s_ridx[tid] = ridx[j * RIDX_J + rows_base + min(tid, valid_rows - 1)];
    __syncthreads();

    const _Float16* wj = Wh + (size_t)j * WHJ;
    const float* qv = attn_q + j * HH;
    const float* bv = attn_b + j * HH;

    if (meta[5] == 2)
        scores_reg<2>(Hh, wj, qv, bv, scores, s_ridx, Alds, Blds, s_red,
                      j, nblk, valid_rows, tid);
    else
        scores_reg<1>(Hh, wj, qv, bv, scores, s_ridx, Alds, Blds, s_red,
                      j, nblk, valid_rows, tid);
}

// ---------------------------------------------------------------------------
// Kernel 2: fused softmax + segmented pooling. Grid (bj, seg): each block
// computes full-span softmax stats, then pools rows [i0,i1) with a x4
// row-unrolled pipeline; partials atomicAdd'ed into pre-zeroed out.
// ---------------------------------------------------------------------------
__global__ __launch_bounds__(256) void k_pool(
    const _Float16* __restrict__ Hh, const float* __restrict__ scores,
    const int* __restrict__ spans, float* __restrict__ out)
{
    const int bj = blockIdx.x, seg = blockIdx.y;
    const int b = bj / JJ, j = bj % JJ;
    const int start = spans[bj * 2 + 0];
    const int end   = spans[bj * 2 + 1];
    const int count = end - start;
    if (count <= 0) return;                    // out already zeroed

    const int tid = threadIdx.x;
    const float* sc = scores + bj * SS;
    __shared__ float red[8];
    __shared__ float wl[SS / NSEG + 1];

    // --- softmax stats over the FULL span ---
    float lm = -3.0e38f;
    for (int s = start + tid; s < end; s += 256) lm = fmaxf(lm, sc[s]);
#pragma unroll
    for (int off = 32; off > 0; off >>= 1) lm = fmaxf(lm, __shfl_xor(lm, off, 64));
    int wid = tid >> 6, lane = tid & 63;
    if (lane == 0) red[wid] = lm;
    __syncthreads();
    float m = fmaxf(fmaxf(red[0], red[1]), fmaxf(red[2], red[3]));

    float ld = 0.f;
    for (int s = start + tid; s < end; s += 256) ld += __expf(sc[s] - m);
#pragma unroll
    for (int off = 32; off > 0; off >>= 1) ld += __shfl_xor(ld, off, 64);
    if (lane == 0) red[4 + wid] = ld;
    __syncthreads();
    float inv_d = 1.f / (red[4] + red[5] + red[6] + red[7]);

    // --- this block's row segment ---
    const int i0 = start + (count * seg) / NSEG;
    const int i1 = start + (count * (seg + 1)) / NSEG;
    for (int s = i0 + tid; s < i1; s += 256)
        wl[s - i0] = __expf(sc[s] - m) * inv_d;
    __syncthreads();

    if (tid < 192) {
        float am[4] = {0.f, 0.f, 0.f, 0.f}, aa[4] = {0.f, 0.f, 0.f, 0.f};
        const _Float16* hp = Hh + (size_t)b * SS * HH + tid * 4;
        const int n = i1 - i0;
        int i = 0;
        for (; i + 4 <= n; i += 4) {
            h4_t v0 = *(const h4_t*)(hp + (size_t)(i0 + i + 0) * HH);
            h4_t v1 = *(const h4_t*)(hp + (size_t)(i0 + i + 1) * HH);
            h4_t v2 = *(const h4_t*)(hp + (size_t)(i0 + i + 2) * HH);
            h4_t v3 = *(const h4_t*)(hp + (size_t)(i0 + i + 3) * HH);
            float w0 = wl[i], w1 = wl[i + 1], w2 = wl[i + 2], w3 = wl[i + 3];
#pragma unroll
            for (int c = 0; c < 4; ++c) {
                float x0 = (float)v0[c], x1 = (float)v1[c];
                float x2 = (float)v2[c], x3 = (float)v3[c];
                am[c] += (x0 + x1) + (x2 + x3);
                aa[c] += (w0 * x0 + w1 * x1) + (w2 * x2 + w3 * x3);
            }
        }
        for (; i < n; ++i) {
            h4_t v = *(const h4_t*)(hp + (size_t)(i0 + i) * HH);
            float w = wl[i];
#pragma unroll
            for (int c = 0; c < 4; ++c) {
                float x = (float)v[c];
                am[c] += x;
                aa[c] += w * x;
            }
        }
        float inv = 1.f / (float)count;
        float* fin = out + (size_t)b * FINAL_W + j * (2 * HH);
#pragma unroll
        for (int c = 0; c < 4; ++c) {
            atomicAdd(&fin[tid * 4 + c], am[c] * inv);
            atomicAdd(&fin[HH + tid * 4 + c], aa[c]);
        }
    }
}

// ---------------------------------------------------------------------------
extern "C" void kernel_launch(void* const* d_in, const int* in_sizes, int n_in,
                              void* d_out, int out_size, void* d_ws, size_t ws_size,
                              hipStream_t stream)
{
    const float* hidden   = (const float*)d_in[0];
    const float* full_emb = (const float*)d_in[1];
    const float* attn_W   = (const float*)d_in[2];
    const float* attn_b   = (const float*)d_in[3];
    const float* attn_q   = (const float*)d_in[4];
    const int*   spans    = (const int*)d_in[5];
    float* out = (float*)d_out;

    char* ws = (char*)d_ws;
    _Float16* Wh  = (_Float16*)ws;
    _Float16* Hh  = (_Float16*)(ws + WH_BYTES);
    float* scores = (float*)(ws + WH_BYTES + HID_BYTES);
    int*   ridx   = (int*)(ws + WH_BYTES + HID_BYTES + SC_BYTES);
    int*   meta   = (int*)(ws + WH_BYTES + HID_BYTES + SC_BYTES + RIDX_BYTES);

    k_convert<<<NB_CONV + NB_IDX + NB_TAIL, 256, 0, stream>>>(
        attn_W, hidden, full_emb, spans, Wh, Hh, scores, ridx, meta, out);
    k_scores<<<dim3(RIDX_J / 128, HH / 128, JJ), 256, 0, stream>>>(
        Hh, Wh, attn_b, attn_q, scores, ridx, meta);
    k_pool<<<dim3(BB * JJ, NSEG), 256, 0, stream>>>(Hh, scores, spans, out);
}